// Round 4
// baseline (296.476 us; speedup 1.0000x reference)
//
#include <hip/hip_runtime.h>

// ImplicitMLP, all GEMMs on MFMA (bf16 in / fp32 acc), per-lane fp32 D/E tail.
// 128-thread blocks = 2 independent waves, each wave = 64 pixels with its own
// 10240 B LDS slice; NO __syncthreads (intra-wave DS ordering + lgkmcnt fences).
// B1/C1 epilogues pack (even,odd)-nt column pairs with v_cvt_pk_bf16_f32 into
// single b32 LDS writes; the resulting column interleave is compensated by a
// static k-permutation in the packed weights: k = rd*32 + (oj&1)*16 + (oj>>1).
//
// Per-wave LDS slice (10240 B), regions reused:
//   Y16 @0 [64][72] bf16 (9216 B)  A->B1 transform, col-pair interleaved, 2-pass
//   X16 @0 [2][64][40] bf16 (2x5120) B1->B2 / C1->C2 staging, double-buffered
//   Z16 @0 [64][40] bf16            z staging (aliases X16 buf0)
//   O3f @0 [64][33] f32  (8448 B)   o3 hand-off to per-lane D/E
//
// ws (prep_pack): bf16 @short-idx:
//   R1p 0      [kt8][n80][k32]   k = interleaved sin/cos feature order
//   L1p 20480  [kt3][n256][k32]  k-permuted (pair interleave), r>=70 zero
//   R2p 45056  [rd8][n16][k32]   k-permuted, n>=10 zero
//   L2p 49152  [nt8][n16][k32]   straight k, k>=10 zero
//   W3p 53248  [rd4][nt2_2][n16][k32] k-permuted
// f32 @dword 28672: W4T [q32][p16]

typedef __attribute__((ext_vector_type(8))) short bf16x8;
typedef __attribute__((ext_vector_type(4))) float f32x4;
typedef __attribute__((ext_vector_type(4))) int i32x4;

#define LFENCE() asm volatile("s_waitcnt lgkmcnt(0)" ::: "memory")

__device__ inline unsigned short f2bf(float f) {       // RNE (prep)
  unsigned u = __float_as_uint(f);
  return (unsigned short)((u + 0x7FFFu + ((u >> 16) & 1u)) >> 16);
}

#if __has_builtin(__builtin_amdgcn_cvt_pk_bf16_f32)
typedef __attribute__((ext_vector_type(2))) __bf16 bf16x2;
__device__ inline unsigned pk2bf(float a, float b) {   // low=a, high=b (RNE)
  bf16x2 v = __builtin_amdgcn_cvt_pk_bf16_f32(a, b);
  return __builtin_bit_cast(unsigned, v);
}
#else
__device__ inline unsigned pk2bf(float a, float b) {   // round-half-up fallback
  return ((__float_as_uint(a) + 0x8000u) >> 16) |
         ((__float_as_uint(b) + 0x8000u) & 0xFFFF0000u);
}
#endif

__global__ __launch_bounds__(256) void prep_pack(
    const float* __restrict__ R1, const float* __restrict__ L1,
    const float* __restrict__ R2, const float* __restrict__ L2,
    const float* __restrict__ W3, const float* __restrict__ W4,
    void* __restrict__ ws) {
  unsigned short* w16 = (unsigned short*)ws;
  float* wf = (float*)ws;
  int e = blockIdx.x * 256 + threadIdx.x;
  if (e < 20480) {                       // R1p: B[k=feat][n=r]
    int kt = e / 2560, rem = e % 2560;
    int n = rem >> 5, oj = rem & 31;
    int k = kt * 32 + oj;
    int feat = (k & 1) ? 128 + (k >> 1) : (k >> 1);
    w16[e] = f2bf((n < 70) ? R1[n * 256 + feat] : 0.0f);
  } else if (e < 45056) {                // L1p: B[k=r][n=j], k pair-permuted
    int f = e - 20480;
    int kt = f / 8192, rem = f % 8192;
    int n = rem >> 5, oj = rem & 31;
    int r = kt * 32 + (oj & 1) * 16 + (oj >> 1);
    w16[e] = f2bf((r < 70) ? L1[n * 70 + r] : 0.0f);
  } else if (e < 49152) {                // R2p: B[k=j][n=t], k pair-permuted
    int g = e - 45056;
    int rd = g / 512, rem = g % 512;
    int n = rem >> 5, oj = rem & 31;
    int j = rd * 32 + (oj & 1) * 16 + (oj >> 1);
    w16[e] = f2bf((n < 10) ? R2[n * 256 + j] : 0.0f);
  } else if (e < 53248) {                // L2p: B[k=t][n=i], straight k
    int f = e - 49152;
    int j = f & 7, h = (f >> 3) & 3, n = (f >> 5) & 15, nt = f >> 9;
    int k = h * 8 + j;
    w16[e] = f2bf((k < 10) ? L2[(nt * 16 + n) * 10 + k] : 0.0f);
  } else if (e < 57344) {                // W3p: B[k=i][n=q], k pair-permuted
    int f = e - 53248;
    int oj = f & 31, n = (f >> 5) & 15, nt2 = (f >> 9) & 1, rd = f >> 10;
    int i = rd * 32 + (oj & 1) * 16 + (oj >> 1);
    w16[e] = f2bf(W3[(nt2 * 16 + n) * 128 + i]);
  } else if (e < 57856) {                // W4T[q][p] = W4[p][q], f32
    int h2 = e - 57344;
    int q = h2 >> 4, p = h2 & 15;
    wf[28672 + h2] = W4[p * 32 + q];
  }
}

__global__ __launch_bounds__(128, 4) void mlp_mfma(
    const float* __restrict__ coords, const float* __restrict__ Bm,
    const float* __restrict__ b1, const float* __restrict__ b2,
    const float* __restrict__ b3v, const float* __restrict__ b4v,
    const float* __restrict__ W5, const float* __restrict__ b5,
    const void* __restrict__ ws, float* __restrict__ out) {
  const int l = threadIdx.x & 63;
  const int wv = threadIdx.x >> 6;
  const int lo = l & 15, hi = l >> 4;
  const int pix0 = blockIdx.x * 128 + wv * 64;

  __shared__ __align__(16) char smem[20480];
  char* slice = smem + wv * 10240;
  unsigned short* Y16 = (unsigned short*)slice;   // [64][72]
  unsigned short* X16 = (unsigned short*)slice;   // [2][64][40]
  float* O3f = (float*)slice;                     // [64][33]

  const unsigned short* R1p = (const unsigned short*)ws;
  const unsigned short* L1p = ((const unsigned short*)ws) + 20480;
  const unsigned short* R2p = ((const unsigned short*)ws) + 45056;
  const unsigned short* L2p = ((const unsigned short*)ws) + 49152;
  const unsigned short* W3p = ((const unsigned short*)ws) + 53248;
  const float* W4T = ((const float*)ws) + 28672;

  const f32x4 fz = {0.0f, 0.0f, 0.0f, 0.0f};

  float c0m[4], c1m[4];
#pragma unroll
  for (int mt = 0; mt < 4; ++mt) {
    int p = pix0 + mt * 16 + lo;
    int bb = p >> 12, hw = p & 4095;
    c0m[mt] = coords[bb * 8192 + hw];
    c1m[mt] = coords[bb * 8192 + 4096 + hw];
  }

  // ---- Phase A: y = X @ R1T, A-frags built in registers (sin|cos packed)
  f32x4 y[4][5];
#pragma unroll
  for (int mt = 0; mt < 4; ++mt)
#pragma unroll
    for (int nt = 0; nt < 5; ++nt) y[mt][nt] = fz;

  float bm0[4], bm1[4];
#pragma unroll
  for (int p = 0; p < 4; ++p) {
    int m = hi * 4 + p;
    bm0[p] = Bm[m]; bm1[p] = Bm[128 + m];
  }
  for (int kt = 0; kt < 8; ++kt) {
    float nb0[4], nb1[4];
    if (kt < 7) {
#pragma unroll
      for (int p = 0; p < 4; ++p) {
        int m = (kt + 1) * 16 + hi * 4 + p;
        nb0[p] = Bm[m]; nb1[p] = Bm[128 + m];
      }
    }
    bf16x8 bfr[5];
#pragma unroll
    for (int nt = 0; nt < 5; ++nt)
      bfr[nt] = *(const bf16x8*)(R1p + ((kt * 80 + nt * 16 + lo) * 4 + hi) * 8);
    bf16x8 af[4];
#pragma unroll
    for (int mt = 0; mt < 4; ++mt) {
#pragma unroll
      for (int p = 0; p < 4; ++p) {
        float u = fmaf(c0m[mt], bm0[p], c1m[mt] * bm1[p]);
        float t = u - floorf(u);               // v_sin/v_cos in revolutions
        float s = __builtin_amdgcn_sinf(t);
        float c = __builtin_amdgcn_cosf(t);
        ((unsigned*)&af[mt])[p] = pk2bf(s, c); // low=sin(even k), high=cos
      }
    }
#pragma unroll
    for (int mt = 0; mt < 4; ++mt)
#pragma unroll
      for (int nt = 0; nt < 5; ++nt)
        y[mt][nt] = __builtin_amdgcn_mfma_f32_16x16x32_bf16(af[mt], bfr[nt],
                                                            y[mt][nt], 0, 0, 0);
#pragma unroll
    for (int p = 0; p < 4; ++p) { bm0[p] = nb0[p]; bm1[p] = nb1[p]; }
  }

  // ---- y -> Y16 (col-pair interleaved), pass 1: nt pairs (0,1),(2,3)
#pragma unroll
  for (int mt = 0; mt < 4; ++mt)
#pragma unroll
    for (int r = 0; r < 4; ++r) {
      int row = mt * 16 + hi * 4 + r;
      *(unsigned*)(Y16 + row * 72 + lo * 2)      = pk2bf(y[mt][0][r], y[mt][1][r]);
      *(unsigned*)(Y16 + row * 72 + 32 + lo * 2) = pk2bf(y[mt][2][r], y[mt][3][r]);
    }
  LFENCE();
  bf16x8 ay[4][3];
#pragma unroll
  for (int mt = 0; mt < 4; ++mt)
#pragma unroll
    for (int kt = 0; kt < 2; ++kt)
      ay[mt][kt] = *(const bf16x8*)(Y16 + (mt * 16 + lo) * 72 + kt * 32 + hi * 8);
  LFENCE();
  // pass 2: nt=4 (+ zero partner) reuses cols 0..31
#pragma unroll
  for (int mt = 0; mt < 4; ++mt)
#pragma unroll
    for (int r = 0; r < 4; ++r) {
      int row = mt * 16 + hi * 4 + r;
      *(unsigned*)(Y16 + row * 72 + lo * 2) = pk2bf(y[mt][4][r], 0.0f);
    }
  LFENCE();
#pragma unroll
  for (int mt = 0; mt < 4; ++mt)
    ay[mt][2] = *(const bf16x8*)(Y16 + (mt * 16 + lo) * 72 + hi * 8);
  LFENCE();

  // ---- B1 (a1 = relu(y@L1T+b1)) in nt-pairs, interleaved with B2 (z += a1@R2T)
  f32x4 zfr[4];
#pragma unroll
  for (int mt = 0; mt < 4; ++mt) zfr[mt] = fz;

#pragma unroll
  for (int rd = 0; rd < 8; ++rd) {
    unsigned short* Xb = X16 + (rd & 1) * 2560;
    bf16x8 blE[3], blO[3];
#pragma unroll
    for (int kt = 0; kt < 3; ++kt) {
      blE[kt] = *(const bf16x8*)(L1p + ((kt * 256 + (2 * rd) * 16 + lo) * 4 + hi) * 8);
      blO[kt] = *(const bf16x8*)(L1p + ((kt * 256 + (2 * rd + 1) * 16 + lo) * 4 + hi) * 8);
    }
    float biasE = b1[2 * rd * 16 + lo];
    float biasO = b1[(2 * rd + 1) * 16 + lo];
    f32x4 cfE[4], cfO[4];
#pragma unroll
    for (int mt = 0; mt < 4; ++mt) { cfE[mt] = fz; cfO[mt] = fz; }
#pragma unroll
    for (int kt = 0; kt < 3; ++kt)
#pragma unroll
      for (int mt = 0; mt < 4; ++mt) {
        cfE[mt] = __builtin_amdgcn_mfma_f32_16x16x32_bf16(ay[mt][kt], blE[kt],
                                                          cfE[mt], 0, 0, 0);
        cfO[mt] = __builtin_amdgcn_mfma_f32_16x16x32_bf16(ay[mt][kt], blO[kt],
                                                          cfO[mt], 0, 0, 0);
      }
#pragma unroll
    for (int mt = 0; mt < 4; ++mt)
#pragma unroll
      for (int r = 0; r < 4; ++r) {
        float v0 = fmaxf(cfE[mt][r] + biasE, 0.0f);
        float v1 = fmaxf(cfO[mt][r] + biasO, 0.0f);
        *(unsigned*)(Xb + (mt * 16 + hi * 4 + r) * 40 + lo * 2) = pk2bf(v0, v1);
      }
    LFENCE();
    bf16x8 br = *(const bf16x8*)(R2p + (rd * 16 + lo) * 32 + hi * 8);
#pragma unroll
    for (int mt = 0; mt < 4; ++mt) {
      bf16x8 aa = *(const bf16x8*)(Xb + (mt * 16 + lo) * 40 + hi * 8);
      zfr[mt] = __builtin_amdgcn_mfma_f32_16x16x32_bf16(aa, br, zfr[mt], 0, 0, 0);
    }
    // no trailing fence: next rd writes the other buffer; DS is in-order per wave
  }

  // ---- z -> Z16 (straight cols, 16..31 zero), reload as A-frags
  unsigned short* Z16 = X16;                    // aliases buf0 (stride 40)
#pragma unroll
  for (int mt = 0; mt < 4; ++mt)
#pragma unroll
    for (int r = 0; r < 4; ++r)
      Z16[(mt * 16 + hi * 4 + r) * 40 + lo] =
          (unsigned short)(pk2bf(zfr[mt][r], 0.0f) & 0xFFFFu);
  *(i32x4*)(Z16 + l * 40 + 16) = (i32x4){0, 0, 0, 0};
  *(i32x4*)(Z16 + l * 40 + 24) = (i32x4){0, 0, 0, 0};
  LFENCE();
  bf16x8 az[4];
#pragma unroll
  for (int mt = 0; mt < 4; ++mt)
    az[mt] = *(const bf16x8*)(Z16 + (mt * 16 + lo) * 40 + hi * 8);
  LFENCE();

  // ---- C1 (a2 = relu(z@L2T+b2)) in nt-pairs, interleaved with C2 (o3 += a2@W3T)
  f32x4 o3fr[4][2];
#pragma unroll
  for (int mt = 0; mt < 4; ++mt) { o3fr[mt][0] = fz; o3fr[mt][1] = fz; }

#pragma unroll
  for (int rd = 0; rd < 4; ++rd) {
    unsigned short* Xb = X16 + (rd & 1) * 2560;
    bf16x8 wlE = *(const bf16x8*)(L2p + ((2 * rd) * 16 + lo) * 32 + hi * 8);
    bf16x8 wlO = *(const bf16x8*)(L2p + ((2 * rd + 1) * 16 + lo) * 32 + hi * 8);
    float biasE = b2[2 * rd * 16 + lo];
    float biasO = b2[(2 * rd + 1) * 16 + lo];
    f32x4 cfE[4], cfO[4];
#pragma unroll
    for (int mt = 0; mt < 4; ++mt) {
      cfE[mt] = __builtin_amdgcn_mfma_f32_16x16x32_bf16(az[mt], wlE, fz, 0, 0, 0);
      cfO[mt] = __builtin_amdgcn_mfma_f32_16x16x32_bf16(az[mt], wlO, fz, 0, 0, 0);
    }
#pragma unroll
    for (int mt = 0; mt < 4; ++mt)
#pragma unroll
      for (int r = 0; r < 4; ++r) {
        float v0 = fmaxf(cfE[mt][r] + biasE, 0.0f);
        float v1 = fmaxf(cfO[mt][r] + biasO, 0.0f);
        *(unsigned*)(Xb + (mt * 16 + hi * 4 + r) * 40 + lo * 2) = pk2bf(v0, v1);
      }
    LFENCE();
    bf16x8 bw0 = *(const bf16x8*)(W3p + ((rd * 2 + 0) * 16 + lo) * 32 + hi * 8);
    bf16x8 bw1 = *(const bf16x8*)(W3p + ((rd * 2 + 1) * 16 + lo) * 32 + hi * 8);
#pragma unroll
    for (int mt = 0; mt < 4; ++mt) {
      bf16x8 aa = *(const bf16x8*)(Xb + (mt * 16 + lo) * 40 + hi * 8);
      o3fr[mt][0] = __builtin_amdgcn_mfma_f32_16x16x32_bf16(aa, bw0, o3fr[mt][0],
                                                            0, 0, 0);
      o3fr[mt][1] = __builtin_amdgcn_mfma_f32_16x16x32_bf16(aa, bw1, o3fr[mt][1],
                                                            0, 0, 0);
    }
  }

  // ---- o3 (+b3, relu) -> O3f f32 hand-off
  LFENCE();
#pragma unroll
  for (int mt = 0; mt < 4; ++mt)
#pragma unroll
    for (int nt2 = 0; nt2 < 2; ++nt2)
#pragma unroll
      for (int r = 0; r < 4; ++r)
        O3f[(mt * 16 + hi * 4 + r) * 33 + nt2 * 16 + lo] =
            fmaxf(o3fr[mt][nt2][r] + b3v[nt2 * 16 + lo], 0.0f);
  LFENCE();

  // ---- Per-lane fp32 D/E (uniform weights -> s_load)
  float o3l[32];
#pragma unroll
  for (int q = 0; q < 32; ++q) o3l[q] = O3f[l * 33 + q];

  float o4[16];
#pragma unroll
  for (int p = 0; p < 16; ++p) o4[p] = b4v[p];
#pragma unroll
  for (int q = 0; q < 32; ++q) {
    float a = o3l[q];                           // already relu'd
    const float* __restrict__ w4 = W4T + q * 16;
#pragma unroll
    for (int p = 0; p < 16; ++p) o4[p] = fmaf(a, w4[p], o4[p]);
  }
#pragma unroll
  for (int p = 0; p < 16; ++p) o4[p] = fmaxf(o4[p], 0.0f);

#pragma unroll
  for (int e = 0; e < 3; ++e) {
    float acc = b5[e];
    const float* __restrict__ w5 = W5 + e * 16;
#pragma unroll
    for (int p = 0; p < 16; ++p) acc = fmaf(o4[p], w5[p], acc);
    out[(pix0 + l) * 3 + e] = acc;
  }
}

extern "C" void kernel_launch(void* const* d_in, const int* in_sizes, int n_in,
                              void* d_out, int out_size, void* d_ws, size_t ws_size,
                              hipStream_t stream) {
  const float* coords = (const float*)d_in[0];
  const float* Bmat   = (const float*)d_in[1];
  const float* L1     = (const float*)d_in[2];
  const float* R1     = (const float*)d_in[3];
  const float* b1     = (const float*)d_in[4];
  const float* L2     = (const float*)d_in[5];
  const float* R2     = (const float*)d_in[6];
  const float* b2     = (const float*)d_in[7];
  const float* W3     = (const float*)d_in[8];
  const float* b3     = (const float*)d_in[9];
  const float* W4     = (const float*)d_in[10];
  const float* b4     = (const float*)d_in[11];
  const float* W5     = (const float*)d_in[12];
  const float* b5     = (const float*)d_in[13];

  prep_pack<<<227, 256, 0, stream>>>(R1, L1, R2, L2, W3, W4, d_ws);
  mlp_mfma<<<4096, 128, 0, stream>>>(coords, Bmat, b1, b2, b3, b4, W5, b5,
                                     d_ws, (float*)d_out);
}

// Round 5
// 184.908 us; speedup vs baseline: 1.6034x; 1.6034x over previous
//
#include <hip/hip_runtime.h>

// ImplicitMLP, all GEMMs on MFMA (bf16 in / fp32 acc), per-lane fp32 D/E tail.
// 128-thread blocks = 2 independent waves, each wave = 64 pixels with its own
// 10240 B LDS slice; NO __syncthreads (intra-wave DS ordering + lgkmcnt fences).
// B1/C1 epilogues pack (even,odd)-nt column pairs with v_cvt_pk_bf16_f32 into
// single b32 LDS writes; the resulting column interleave is compensated by a
// static k-permutation in the packed weights: k = rd*32 + (oj&1)*16 + (oj>>1).
//
// __launch_bounds__(128, 2): round 4's (128,4) capped VGPRs at 64 -> 400 MB of
// scratch spill traffic (FETCH 242 MB / WRITE 408 MB). (128,2) lets the
// allocator keep the ~90-VGPR working set in registers; 16 waves/CU still
// comes from LDS (8 blocks x 20480 B = 160 KiB exactly).
//
// Per-wave LDS slice (10240 B), regions reused:
//   Y16 @0 [64][72] bf16 (9216 B)  A->B1 transform, col-pair interleaved, 2-pass
//   X16 @0 [2][64][40] bf16 (2x5120) B1->B2 / C1->C2 staging, double-buffered
//   Z16 @0 [64][40] bf16            z staging (aliases X16 buf0)
//   O3f @0 [64][33] f32  (8448 B)   o3 hand-off to per-lane D/E
//
// ws (prep_pack): bf16 @short-idx:
//   R1p 0      [kt8][n80][k32]   k = interleaved sin/cos feature order
//   L1p 20480  [kt3][n256][k32]  k-permuted (pair interleave), r>=70 zero
//   R2p 45056  [rd8][n16][k32]   k-permuted, n>=10 zero
//   L2p 49152  [nt8][n16][k32]   straight k, k>=10 zero
//   W3p 53248  [rd4][nt2_2][n16][k32] k-permuted
// f32 @dword 28672: W4T [q32][p16]

typedef __attribute__((ext_vector_type(8))) short bf16x8;
typedef __attribute__((ext_vector_type(4))) float f32x4;
typedef __attribute__((ext_vector_type(4))) int i32x4;

#define LFENCE() asm volatile("s_waitcnt lgkmcnt(0)" ::: "memory")

__device__ inline unsigned short f2bf(float f) {       // RNE (prep)
  unsigned u = __float_as_uint(f);
  return (unsigned short)((u + 0x7FFFu + ((u >> 16) & 1u)) >> 16);
}

#if __has_builtin(__builtin_amdgcn_cvt_pk_bf16_f32)
typedef __attribute__((ext_vector_type(2))) __bf16 bf16x2;
__device__ inline unsigned pk2bf(float a, float b) {   // low=a, high=b (RNE)
  bf16x2 v = __builtin_amdgcn_cvt_pk_bf16_f32(a, b);
  return __builtin_bit_cast(unsigned, v);
}
#else
__device__ inline unsigned pk2bf(float a, float b) {   // round-half-up fallback
  return ((__float_as_uint(a) + 0x8000u) >> 16) |
         ((__float_as_uint(b) + 0x8000u) & 0xFFFF0000u);
}
#endif

__global__ __launch_bounds__(256) void prep_pack(
    const float* __restrict__ R1, const float* __restrict__ L1,
    const float* __restrict__ R2, const float* __restrict__ L2,
    const float* __restrict__ W3, const float* __restrict__ W4,
    void* __restrict__ ws) {
  unsigned short* w16 = (unsigned short*)ws;
  float* wf = (float*)ws;
  int e = blockIdx.x * 256 + threadIdx.x;
  if (e < 20480) {                       // R1p: B[k=feat][n=r]
    int kt = e / 2560, rem = e % 2560;
    int n = rem >> 5, oj = rem & 31;
    int k = kt * 32 + oj;
    int feat = (k & 1) ? 128 + (k >> 1) : (k >> 1);
    w16[e] = f2bf((n < 70) ? R1[n * 256 + feat] : 0.0f);
  } else if (e < 45056) {                // L1p: B[k=r][n=j], k pair-permuted
    int f = e - 20480;
    int kt = f / 8192, rem = f % 8192;
    int n = rem >> 5, oj = rem & 31;
    int r = kt * 32 + (oj & 1) * 16 + (oj >> 1);
    w16[e] = f2bf((r < 70) ? L1[n * 70 + r] : 0.0f);
  } else if (e < 49152) {                // R2p: B[k=j][n=t], k pair-permuted
    int g = e - 45056;
    int rd = g / 512, rem = g % 512;
    int n = rem >> 5, oj = rem & 31;
    int j = rd * 32 + (oj & 1) * 16 + (oj >> 1);
    w16[e] = f2bf((n < 10) ? R2[n * 256 + j] : 0.0f);
  } else if (e < 53248) {                // L2p: B[k=t][n=i], straight k
    int f = e - 49152;
    int j = f & 7, h = (f >> 3) & 3, n = (f >> 5) & 15, nt = f >> 9;
    int k = h * 8 + j;
    w16[e] = f2bf((k < 10) ? L2[(nt * 16 + n) * 10 + k] : 0.0f);
  } else if (e < 57344) {                // W3p: B[k=i][n=q], k pair-permuted
    int f = e - 53248;
    int oj = f & 31, n = (f >> 5) & 15, nt2 = (f >> 9) & 1, rd = f >> 10;
    int i = rd * 32 + (oj & 1) * 16 + (oj >> 1);
    w16[e] = f2bf(W3[(nt2 * 16 + n) * 128 + i]);
  } else if (e < 57856) {                // W4T[q][p] = W4[p][q], f32
    int h2 = e - 57344;
    int q = h2 >> 4, p = h2 & 15;
    wf[28672 + h2] = W4[p * 32 + q];
  }
}

__global__ __launch_bounds__(128, 2) void mlp_mfma(
    const float* __restrict__ coords, const float* __restrict__ Bm,
    const float* __restrict__ b1, const float* __restrict__ b2,
    const float* __restrict__ b3v, const float* __restrict__ b4v,
    const float* __restrict__ W5, const float* __restrict__ b5,
    const void* __restrict__ ws, float* __restrict__ out) {
  const int l = threadIdx.x & 63;
  const int wv = threadIdx.x >> 6;
  const int lo = l & 15, hi = l >> 4;
  const int pix0 = blockIdx.x * 128 + wv * 64;

  __shared__ __align__(16) char smem[20480];
  char* slice = smem + wv * 10240;
  unsigned short* Y16 = (unsigned short*)slice;   // [64][72]
  unsigned short* X16 = (unsigned short*)slice;   // [2][64][40]
  float* O3f = (float*)slice;                     // [64][33]

  const unsigned short* R1p = (const unsigned short*)ws;
  const unsigned short* L1p = ((const unsigned short*)ws) + 20480;
  const unsigned short* R2p = ((const unsigned short*)ws) + 45056;
  const unsigned short* L2p = ((const unsigned short*)ws) + 49152;
  const unsigned short* W3p = ((const unsigned short*)ws) + 53248;
  const float* W4T = ((const float*)ws) + 28672;

  const f32x4 fz = {0.0f, 0.0f, 0.0f, 0.0f};

  float c0m[4], c1m[4];
#pragma unroll
  for (int mt = 0; mt < 4; ++mt) {
    int p = pix0 + mt * 16 + lo;
    int bb = p >> 12, hw = p & 4095;
    c0m[mt] = coords[bb * 8192 + hw];
    c1m[mt] = coords[bb * 8192 + 4096 + hw];
  }

  // ---- Phase A: y = X @ R1T, A-frags built in registers (sin|cos packed)
  f32x4 y[4][5];
#pragma unroll
  for (int mt = 0; mt < 4; ++mt)
#pragma unroll
    for (int nt = 0; nt < 5; ++nt) y[mt][nt] = fz;

  float bm0[4], bm1[4];
#pragma unroll
  for (int p = 0; p < 4; ++p) {
    int m = hi * 4 + p;
    bm0[p] = Bm[m]; bm1[p] = Bm[128 + m];
  }
  for (int kt = 0; kt < 8; ++kt) {
    float nb0[4], nb1[4];
    if (kt < 7) {
#pragma unroll
      for (int p = 0; p < 4; ++p) {
        int m = (kt + 1) * 16 + hi * 4 + p;
        nb0[p] = Bm[m]; nb1[p] = Bm[128 + m];
      }
    }
    bf16x8 bfr[5];
#pragma unroll
    for (int nt = 0; nt < 5; ++nt)
      bfr[nt] = *(const bf16x8*)(R1p + ((kt * 80 + nt * 16 + lo) * 4 + hi) * 8);
    bf16x8 af[4];
#pragma unroll
    for (int mt = 0; mt < 4; ++mt) {
#pragma unroll
      for (int p = 0; p < 4; ++p) {
        float u = fmaf(c0m[mt], bm0[p], c1m[mt] * bm1[p]);
        float t = u - floorf(u);               // v_sin/v_cos in revolutions
        float s = __builtin_amdgcn_sinf(t);
        float c = __builtin_amdgcn_cosf(t);
        ((unsigned*)&af[mt])[p] = pk2bf(s, c); // low=sin(even k), high=cos
      }
    }
#pragma unroll
    for (int mt = 0; mt < 4; ++mt)
#pragma unroll
      for (int nt = 0; nt < 5; ++nt)
        y[mt][nt] = __builtin_amdgcn_mfma_f32_16x16x32_bf16(af[mt], bfr[nt],
                                                            y[mt][nt], 0, 0, 0);
#pragma unroll
    for (int p = 0; p < 4; ++p) { bm0[p] = nb0[p]; bm1[p] = nb1[p]; }
  }

  // ---- y -> Y16 (col-pair interleaved), pass 1: nt pairs (0,1),(2,3)
#pragma unroll
  for (int mt = 0; mt < 4; ++mt)
#pragma unroll
    for (int r = 0; r < 4; ++r) {
      int row = mt * 16 + hi * 4 + r;
      *(unsigned*)(Y16 + row * 72 + lo * 2)      = pk2bf(y[mt][0][r], y[mt][1][r]);
      *(unsigned*)(Y16 + row * 72 + 32 + lo * 2) = pk2bf(y[mt][2][r], y[mt][3][r]);
    }
  LFENCE();
  bf16x8 ay[4][3];
#pragma unroll
  for (int mt = 0; mt < 4; ++mt)
#pragma unroll
    for (int kt = 0; kt < 2; ++kt)
      ay[mt][kt] = *(const bf16x8*)(Y16 + (mt * 16 + lo) * 72 + kt * 32 + hi * 8);
  LFENCE();
  // pass 2: nt=4 (+ zero partner) reuses cols 0..31
#pragma unroll
  for (int mt = 0; mt < 4; ++mt)
#pragma unroll
    for (int r = 0; r < 4; ++r) {
      int row = mt * 16 + hi * 4 + r;
      *(unsigned*)(Y16 + row * 72 + lo * 2) = pk2bf(y[mt][4][r], 0.0f);
    }
  LFENCE();
#pragma unroll
  for (int mt = 0; mt < 4; ++mt)
    ay[mt][2] = *(const bf16x8*)(Y16 + (mt * 16 + lo) * 72 + hi * 8);
  LFENCE();

  // ---- B1 (a1 = relu(y@L1T+b1)) in nt-pairs, interleaved with B2 (z += a1@R2T)
  f32x4 zfr[4];
#pragma unroll
  for (int mt = 0; mt < 4; ++mt) zfr[mt] = fz;

#pragma unroll
  for (int rd = 0; rd < 8; ++rd) {
    unsigned short* Xb = X16 + (rd & 1) * 2560;
    bf16x8 blE[3], blO[3];
#pragma unroll
    for (int kt = 0; kt < 3; ++kt) {
      blE[kt] = *(const bf16x8*)(L1p + ((kt * 256 + (2 * rd) * 16 + lo) * 4 + hi) * 8);
      blO[kt] = *(const bf16x8*)(L1p + ((kt * 256 + (2 * rd + 1) * 16 + lo) * 4 + hi) * 8);
    }
    float biasE = b1[2 * rd * 16 + lo];
    float biasO = b1[(2 * rd + 1) * 16 + lo];
    f32x4 cfE[4], cfO[4];
#pragma unroll
    for (int mt = 0; mt < 4; ++mt) { cfE[mt] = fz; cfO[mt] = fz; }
#pragma unroll
    for (int kt = 0; kt < 3; ++kt)
#pragma unroll
      for (int mt = 0; mt < 4; ++mt) {
        cfE[mt] = __builtin_amdgcn_mfma_f32_16x16x32_bf16(ay[mt][kt], blE[kt],
                                                          cfE[mt], 0, 0, 0);
        cfO[mt] = __builtin_amdgcn_mfma_f32_16x16x32_bf16(ay[mt][kt], blO[kt],
                                                          cfO[mt], 0, 0, 0);
      }
#pragma unroll
    for (int mt = 0; mt < 4; ++mt)
#pragma unroll
      for (int r = 0; r < 4; ++r) {
        float v0 = fmaxf(cfE[mt][r] + biasE, 0.0f);
        float v1 = fmaxf(cfO[mt][r] + biasO, 0.0f);
        *(unsigned*)(Xb + (mt * 16 + hi * 4 + r) * 40 + lo * 2) = pk2bf(v0, v1);
      }
    LFENCE();
    bf16x8 br = *(const bf16x8*)(R2p + (rd * 16 + lo) * 32 + hi * 8);
#pragma unroll
    for (int mt = 0; mt < 4; ++mt) {
      bf16x8 aa = *(const bf16x8*)(Xb + (mt * 16 + lo) * 40 + hi * 8);
      zfr[mt] = __builtin_amdgcn_mfma_f32_16x16x32_bf16(aa, br, zfr[mt], 0, 0, 0);
    }
    // no trailing fence: next rd writes the other buffer; DS is in-order per wave
  }

  // ---- z -> Z16 (straight cols, 16..31 zero), reload as A-frags
  unsigned short* Z16 = X16;                    // aliases buf0 (stride 40)
#pragma unroll
  for (int mt = 0; mt < 4; ++mt)
#pragma unroll
    for (int r = 0; r < 4; ++r)
      Z16[(mt * 16 + hi * 4 + r) * 40 + lo] =
          (unsigned short)(pk2bf(zfr[mt][r], 0.0f) & 0xFFFFu);
  *(i32x4*)(Z16 + l * 40 + 16) = (i32x4){0, 0, 0, 0};
  *(i32x4*)(Z16 + l * 40 + 24) = (i32x4){0, 0, 0, 0};
  LFENCE();
  bf16x8 az[4];
#pragma unroll
  for (int mt = 0; mt < 4; ++mt)
    az[mt] = *(const bf16x8*)(Z16 + (mt * 16 + lo) * 40 + hi * 8);
  LFENCE();

  // ---- C1 (a2 = relu(z@L2T+b2)) in nt-pairs, interleaved with C2 (o3 += a2@W3T)
  f32x4 o3fr[4][2];
#pragma unroll
  for (int mt = 0; mt < 4; ++mt) { o3fr[mt][0] = fz; o3fr[mt][1] = fz; }

#pragma unroll
  for (int rd = 0; rd < 4; ++rd) {
    unsigned short* Xb = X16 + (rd & 1) * 2560;
    bf16x8 wlE = *(const bf16x8*)(L2p + ((2 * rd) * 16 + lo) * 32 + hi * 8);
    bf16x8 wlO = *(const bf16x8*)(L2p + ((2 * rd + 1) * 16 + lo) * 32 + hi * 8);
    float biasE = b2[2 * rd * 16 + lo];
    float biasO = b2[(2 * rd + 1) * 16 + lo];
    f32x4 cfE[4], cfO[4];
#pragma unroll
    for (int mt = 0; mt < 4; ++mt) {
      cfE[mt] = __builtin_amdgcn_mfma_f32_16x16x32_bf16(az[mt], wlE, fz, 0, 0, 0);
      cfO[mt] = __builtin_amdgcn_mfma_f32_16x16x32_bf16(az[mt], wlO, fz, 0, 0, 0);
    }
#pragma unroll
    for (int mt = 0; mt < 4; ++mt)
#pragma unroll
      for (int r = 0; r < 4; ++r) {
        float v0 = fmaxf(cfE[mt][r] + biasE, 0.0f);
        float v1 = fmaxf(cfO[mt][r] + biasO, 0.0f);
        *(unsigned*)(Xb + (mt * 16 + hi * 4 + r) * 40 + lo * 2) = pk2bf(v0, v1);
      }
    LFENCE();
    bf16x8 bw0 = *(const bf16x8*)(W3p + ((rd * 2 + 0) * 16 + lo) * 32 + hi * 8);
    bf16x8 bw1 = *(const bf16x8*)(W3p + ((rd * 2 + 1) * 16 + lo) * 32 + hi * 8);
#pragma unroll
    for (int mt = 0; mt < 4; ++mt) {
      bf16x8 aa = *(const bf16x8*)(Xb + (mt * 16 + lo) * 40 + hi * 8);
      o3fr[mt][0] = __builtin_amdgcn_mfma_f32_16x16x32_bf16(aa, bw0, o3fr[mt][0],
                                                            0, 0, 0);
      o3fr[mt][1] = __builtin_amdgcn_mfma_f32_16x16x32_bf16(aa, bw1, o3fr[mt][1],
                                                            0, 0, 0);
    }
  }

  // ---- o3 (+b3, relu) -> O3f f32 hand-off
  LFENCE();
#pragma unroll
  for (int mt = 0; mt < 4; ++mt)
#pragma unroll
    for (int nt2 = 0; nt2 < 2; ++nt2)
#pragma unroll
      for (int r = 0; r < 4; ++r)
        O3f[(mt * 16 + hi * 4 + r) * 33 + nt2 * 16 + lo] =
            fmaxf(o3fr[mt][nt2][r] + b3v[nt2 * 16 + lo], 0.0f);
  LFENCE();

  // ---- Per-lane fp32 D/E (uniform weights -> s_load)
  float o3l[32];
#pragma unroll
  for (int q = 0; q < 32; ++q) o3l[q] = O3f[l * 33 + q];

  float o4[16];
#pragma unroll
  for (int p = 0; p < 16; ++p) o4[p] = b4v[p];
#pragma unroll
  for (int q = 0; q < 32; ++q) {
    float a = o3l[q];                           // already relu'd
    const float* __restrict__ w4 = W4T + q * 16;
#pragma unroll
    for (int p = 0; p < 16; ++p) o4[p] = fmaf(a, w4[p], o4[p]);
  }
#pragma unroll
  for (int p = 0; p < 16; ++p) o4[p] = fmaxf(o4[p], 0.0f);

#pragma unroll
  for (int e = 0; e < 3; ++e) {
    float acc = b5[e];
    const float* __restrict__ w5 = W5 + e * 16;
#pragma unroll
    for (int p = 0; p < 16; ++p) acc = fmaf(o4[p], w5[p], acc);
    out[(pix0 + l) * 3 + e] = acc;
  }
}

extern "C" void kernel_launch(void* const* d_in, const int* in_sizes, int n_in,
                              void* d_out, int out_size, void* d_ws, size_t ws_size,
                              hipStream_t stream) {
  const float* coords = (const float*)d_in[0];
  const float* Bmat   = (const float*)d_in[1];
  const float* L1     = (const float*)d_in[2];
  const float* R1     = (const float*)d_in[3];
  const float* b1     = (const float*)d_in[4];
  const float* L2     = (const float*)d_in[5];
  const float* R2     = (const float*)d_in[6];
  const float* b2     = (const float*)d_in[7];
  const float* W3     = (const float*)d_in[8];
  const float* b3     = (const float*)d_in[9];
  const float* W4     = (const float*)d_in[10];
  const float* b4     = (const float*)d_in[11];
  const float* W5     = (const float*)d_in[12];
  const float* b5     = (const float*)d_in[13];

  prep_pack<<<227, 256, 0, stream>>>(R1, L1, R2, L2, W3, W4, d_ws);
  mlp_mfma<<<4096, 128, 0, stream>>>(coords, Bmat, b1, b2, b3, b4, W5, b5,
                                     d_ws, (float*)d_out);
}

// Round 6
// 157.250 us; speedup vs baseline: 1.8854x; 1.1759x over previous
//
#include <hip/hip_runtime.h>

// ImplicitMLP, all GEMMs (A,B1,B2,C1,C2,D) on MFMA bf16/fp32-acc; per-lane E.
// 64-thread 1-wave blocks (r3's empirically-best occupancy), LDS 13312 B.
// Software-pipelined B/C loops: cf(rd) MFMAs -> prev-rd second-GEMM MFMAs
// (covering the LDS read latency) -> epilogue write -> weight prefetch ->
// lgkmcnt fence -> read issue. DS ops are in-order per wave, so cross-buffer
// WAR needs no fences.
//
// LDS (13312 B), regions reused (single wave, in-order DS):
//   Y16 @0 [64][104] bf16 (13312) A->B1 transform, col-pair interleaved, 1 pass
//   X16 @0 [2][64][40] bf16 (2x5120) staging: B1->B2, C1->C2, o3->D (buf0)
//   O4f @0 [64][17] f32 (4352)    o4 hand-off to per-lane E
//
// ws (prep_pack), bf16 @short-idx:
//   R1p 0      [kt8][n80][k32]   k = interleaved sin/cos feature order
//   L1p 20480  [kt3][n256][k32]  k pair-permuted, r>=70 zero
//   R2p 45056  [rd8][n16][k32]   k pair-permuted, n>=10 zero
//   L2p 49152  [nt8][n16][k32]   straight k, k>=10 zero
//   W3p 53248  [rd4][s2][n16][k32] k pair-permuted
//   W4p 57344  [n16][k32]        k pair-permuted

typedef __attribute__((ext_vector_type(8))) short bf16x8;
typedef __attribute__((ext_vector_type(4))) float f32x4;
typedef __attribute__((ext_vector_type(4))) int i32x4;

#define LFENCE() asm volatile("s_waitcnt lgkmcnt(0)" ::: "memory")

__device__ inline unsigned short f2bf(float f) {       // RNE (prep)
  unsigned u = __float_as_uint(f);
  return (unsigned short)((u + 0x7FFFu + ((u >> 16) & 1u)) >> 16);
}

#if __has_builtin(__builtin_amdgcn_cvt_pk_bf16_f32)
typedef __attribute__((ext_vector_type(2))) __bf16 bf16x2;
__device__ inline unsigned pk2bf(float a, float b) {   // low=a, high=b (RNE)
  bf16x2 v = __builtin_amdgcn_cvt_pk_bf16_f32(a, b);
  return __builtin_bit_cast(unsigned, v);
}
#else
__device__ inline unsigned pk2bf(float a, float b) {   // round-half-up fallback
  return ((__float_as_uint(a) + 0x8000u) >> 16) |
         ((__float_as_uint(b) + 0x8000u) & 0xFFFF0000u);
}
#endif

__global__ __launch_bounds__(256) void prep_pack(
    const float* __restrict__ R1, const float* __restrict__ L1,
    const float* __restrict__ R2, const float* __restrict__ L2,
    const float* __restrict__ W3, const float* __restrict__ W4,
    void* __restrict__ ws) {
  unsigned short* w16 = (unsigned short*)ws;
  int e = blockIdx.x * 256 + threadIdx.x;
  if (e < 20480) {                       // R1p: B[k=feat][n=r]
    int kt = e / 2560, rem = e % 2560;
    int n = rem >> 5, oj = rem & 31;
    int k = kt * 32 + oj;
    int feat = (k & 1) ? 128 + (k >> 1) : (k >> 1);
    w16[e] = f2bf((n < 70) ? R1[n * 256 + feat] : 0.0f);
  } else if (e < 45056) {                // L1p: B[k=r][n=j], k pair-permuted
    int f = e - 20480;
    int kt = f / 8192, rem = f % 8192;
    int n = rem >> 5, oj = rem & 31;
    int r = kt * 32 + (oj & 1) * 16 + (oj >> 1);
    w16[e] = f2bf((r < 70) ? L1[n * 70 + r] : 0.0f);
  } else if (e < 49152) {                // R2p: B[k=j][n=t], k pair-permuted
    int g = e - 45056;
    int rd = g / 512, rem = g % 512;
    int n = rem >> 5, oj = rem & 31;
    int j = rd * 32 + (oj & 1) * 16 + (oj >> 1);
    w16[e] = f2bf((n < 10) ? R2[n * 256 + j] : 0.0f);
  } else if (e < 53248) {                // L2p: B[k=t][n=i], straight k
    int f = e - 49152;
    int k = f & 31, n = (f >> 5) & 15, nt = f >> 9;
    w16[e] = f2bf((k < 10) ? L2[(nt * 16 + n) * 10 + k] : 0.0f);
  } else if (e < 57344) {                // W3p: B[k=i][n=q], k pair-permuted
    int f = e - 53248;
    int oj = f & 31, n = (f >> 5) & 15, s = (f >> 9) & 1, rd = f >> 10;
    int i = rd * 32 + (oj & 1) * 16 + (oj >> 1);
    w16[e] = f2bf(W3[(s * 16 + n) * 128 + i]);
  } else if (e < 57856) {                // W4p: B[k=q][n=p], k pair-permuted
    int f = e - 57344;
    int n = f >> 5, oj = f & 31;
    int q = (oj & 1) * 16 + (oj >> 1);
    w16[e] = f2bf(W4[n * 32 + q]);
  }
}

__global__ __launch_bounds__(64, 2) void mlp_mfma(
    const float* __restrict__ coords, const float* __restrict__ Bm,
    const float* __restrict__ b1, const float* __restrict__ b2,
    const float* __restrict__ b3v, const float* __restrict__ b4v,
    const float* __restrict__ W5, const float* __restrict__ b5,
    const void* __restrict__ ws, float* __restrict__ out) {
  const int l = threadIdx.x;
  const int lo = l & 15, hi = l >> 4;
  const int pix0 = blockIdx.x * 64;

  __shared__ __align__(16) char smem[13312];
  unsigned short* Y16 = (unsigned short*)smem;    // [64][104]
  unsigned short* X16 = (unsigned short*)smem;    // [2][64][40]
  float* O4f = (float*)smem;                      // [64][17]

  const unsigned short* R1p = (const unsigned short*)ws;
  const unsigned short* L1p = ((const unsigned short*)ws) + 20480;
  const unsigned short* R2p = ((const unsigned short*)ws) + 45056;
  const unsigned short* L2p = ((const unsigned short*)ws) + 49152;
  const unsigned short* W3p = ((const unsigned short*)ws) + 53248;
  const unsigned short* W4p = ((const unsigned short*)ws) + 57344;

  const f32x4 fz = {0.0f, 0.0f, 0.0f, 0.0f};

  float c0m[4], c1m[4];
#pragma unroll
  for (int mt = 0; mt < 4; ++mt) {
    int p = pix0 + mt * 16 + lo;
    int bb = p >> 12, hw = p & 4095;
    c0m[mt] = coords[bb * 8192 + hw];
    c1m[mt] = coords[bb * 8192 + 4096 + hw];
  }

  // ---- Phase A: y = X @ R1T, A-frags in registers (sin|cos packed)
  f32x4 y[4][5];
#pragma unroll
  for (int mt = 0; mt < 4; ++mt)
#pragma unroll
    for (int nt = 0; nt < 5; ++nt) y[mt][nt] = fz;

  float bm0[4], bm1[4];
#pragma unroll
  for (int p = 0; p < 4; ++p) {
    int m = hi * 4 + p;
    bm0[p] = Bm[m]; bm1[p] = Bm[128 + m];
  }
  for (int kt = 0; kt < 8; ++kt) {
    float nb0[4], nb1[4];
    if (kt < 7) {
#pragma unroll
      for (int p = 0; p < 4; ++p) {
        int m = (kt + 1) * 16 + hi * 4 + p;
        nb0[p] = Bm[m]; nb1[p] = Bm[128 + m];
      }
    }
    bf16x8 bfr[5];
#pragma unroll
    for (int nt = 0; nt < 5; ++nt)
      bfr[nt] = *(const bf16x8*)(R1p + (kt * 80 + nt * 16 + lo) * 32 + hi * 8);
    bf16x8 af[4];
#pragma unroll
    for (int mt = 0; mt < 4; ++mt) {
#pragma unroll
      for (int p = 0; p < 4; ++p) {
        float u = fmaf(c0m[mt], bm0[p], c1m[mt] * bm1[p]);
        float t = u - floorf(u);               // v_sin/v_cos in revolutions
        float s = __builtin_amdgcn_sinf(t);
        float c = __builtin_amdgcn_cosf(t);
        ((unsigned*)&af[mt])[p] = pk2bf(s, c);
      }
    }
#pragma unroll
    for (int mt = 0; mt < 4; ++mt)
#pragma unroll
      for (int nt = 0; nt < 5; ++nt)
        y[mt][nt] = __builtin_amdgcn_mfma_f32_16x16x32_bf16(af[mt], bfr[nt],
                                                            y[mt][nt], 0, 0, 0);
#pragma unroll
    for (int p = 0; p < 4; ++p) { bm0[p] = nb0[p]; bm1[p] = nb1[p]; }
  }

  // ---- y -> Y16 one-shot (pairs: (0,1),(2,3),(4,zero)), single fence
#pragma unroll
  for (int mt = 0; mt < 4; ++mt)
#pragma unroll
    for (int r = 0; r < 4; ++r) {
      int row = mt * 16 + hi * 4 + r;
      *(unsigned*)(Y16 + row * 104 + lo * 2)      = pk2bf(y[mt][0][r], y[mt][1][r]);
      *(unsigned*)(Y16 + row * 104 + 32 + lo * 2) = pk2bf(y[mt][2][r], y[mt][3][r]);
      *(unsigned*)(Y16 + row * 104 + 64 + lo * 2) = pk2bf(y[mt][4][r], 0.0f);
    }

  // B-phase prologue weight loads (global/vmcnt: unaffected by LFENCE)
  bf16x8 WE[3], WO[3], WEn[3], WOn[3];
#pragma unroll
  for (int kt = 0; kt < 3; ++kt) {
    WE[kt] = *(const bf16x8*)(L1p + (kt * 256 + lo) * 32 + hi * 8);
    WO[kt] = *(const bf16x8*)(L1p + (kt * 256 + 16 + lo) * 32 + hi * 8);
  }
  float bE = b1[lo], bO = b1[16 + lo], bEn, bOn;
  bf16x8 br_c = *(const bf16x8*)(R2p + lo * 32 + hi * 8);
  bf16x8 br_u, br_n;

  LFENCE();                                  // drain Y writes
  bf16x8 ay[4][3];
#pragma unroll
  for (int mt = 0; mt < 4; ++mt)
#pragma unroll
    for (int kt = 0; kt < 3; ++kt)
      ay[mt][kt] = *(const bf16x8*)(Y16 + (mt * 16 + lo) * 104 + kt * 32 + hi * 8);
  // Y16 dead after these reads complete; X16 writes below are issued after
  // (in-order DS), so no fence needed.

  // ---- Phase B pipeline: B1(rd) MFMAs | B2(rd-1) MFMAs | write(rd) |
  //                        prefetch(rd+1) | fence | read(rd)
  f32x4 zfr[4];
#pragma unroll
  for (int mt = 0; mt < 4; ++mt) zfr[mt] = fz;
  bf16x8 aa[4];

#pragma unroll
  for (int rd = 0; rd <= 8; ++rd) {
    f32x4 cfE[4], cfO[4];
    if (rd < 8) {
#pragma unroll
      for (int mt = 0; mt < 4; ++mt) { cfE[mt] = fz; cfO[mt] = fz; }
#pragma unroll
      for (int kt = 0; kt < 3; ++kt)
#pragma unroll
        for (int mt = 0; mt < 4; ++mt) {
          cfE[mt] = __builtin_amdgcn_mfma_f32_16x16x32_bf16(ay[mt][kt], WE[kt],
                                                            cfE[mt], 0, 0, 0);
          cfO[mt] = __builtin_amdgcn_mfma_f32_16x16x32_bf16(ay[mt][kt], WO[kt],
                                                            cfO[mt], 0, 0, 0);
        }
    }
    if (rd > 0) {                           // B2(rd-1), reads covered above
#pragma unroll
      for (int mt = 0; mt < 4; ++mt)
        zfr[mt] = __builtin_amdgcn_mfma_f32_16x16x32_bf16(aa[mt], br_u,
                                                          zfr[mt], 0, 0, 0);
    }
    if (rd < 8) {
      unsigned short* Xb = X16 + (rd & 1) * 2560;
#pragma unroll
      for (int mt = 0; mt < 4; ++mt)
#pragma unroll
        for (int r = 0; r < 4; ++r) {
          float v0 = fmaxf(cfE[mt][r] + bE, 0.0f);
          float v1 = fmaxf(cfO[mt][r] + bO, 0.0f);
          *(unsigned*)(Xb + (mt * 16 + hi * 4 + r) * 40 + lo * 2) = pk2bf(v0, v1);
        }
      if (rd < 7) {                         // prefetch rd+1 weights/biases
#pragma unroll
        for (int kt = 0; kt < 3; ++kt) {
          WEn[kt] = *(const bf16x8*)(L1p + (kt * 256 + (2 * rd + 2) * 16 + lo) * 32 + hi * 8);
          WOn[kt] = *(const bf16x8*)(L1p + (kt * 256 + (2 * rd + 3) * 16 + lo) * 32 + hi * 8);
        }
        bEn = b1[(2 * rd + 2) * 16 + lo];
        bOn = b1[(2 * rd + 3) * 16 + lo];
        br_n = *(const bf16x8*)(R2p + ((rd + 1) * 16 + lo) * 32 + hi * 8);
      }
      LFENCE();                             // drain write(rd)
#pragma unroll
      for (int mt = 0; mt < 4; ++mt)
        aa[mt] = *(const bf16x8*)(Xb + (mt * 16 + lo) * 40 + hi * 8);
      br_u = br_c; br_c = br_n;
#pragma unroll
      for (int kt = 0; kt < 3; ++kt) { WE[kt] = WEn[kt]; WO[kt] = WOn[kt]; }
      bE = bEn; bO = bOn;
    }
  }

  // ---- z -> Z16 (buf0, straight cols, 16..31 zero), reload as A-frags
  unsigned short* Z16 = X16;
#pragma unroll
  for (int mt = 0; mt < 4; ++mt)
#pragma unroll
    for (int r = 0; r < 4; ++r)
      Z16[(mt * 16 + hi * 4 + r) * 40 + lo] =
          (unsigned short)(pk2bf(zfr[mt][r], 0.0f) & 0xFFFFu);
  *(i32x4*)(Z16 + l * 40 + 16) = (i32x4){0, 0, 0, 0};
  *(i32x4*)(Z16 + l * 40 + 24) = (i32x4){0, 0, 0, 0};

  // C-phase prologue loads
  bf16x8 wlE = *(const bf16x8*)(L2p + lo * 32 + hi * 8);
  bf16x8 wlO = *(const bf16x8*)(L2p + (16 + lo) * 32 + hi * 8);
  bf16x8 wlEn, wlOn;
  float cE = b2[lo], cO = b2[16 + lo], cEn, cOn;
  bf16x8 bw_c0 = *(const bf16x8*)(W3p + lo * 32 + hi * 8);
  bf16x8 bw_c1 = *(const bf16x8*)(W3p + (16 + lo) * 32 + hi * 8);
  bf16x8 bw_u0, bw_u1, bw_n0, bw_n1;

  LFENCE();                                  // drain Z writes
  bf16x8 az[4];
#pragma unroll
  for (int mt = 0; mt < 4; ++mt)
    az[mt] = *(const bf16x8*)(Z16 + (mt * 16 + lo) * 40 + hi * 8);

  // ---- Phase C pipeline: C1(rd) | C2(rd-1) | write(rd) | prefetch | fence | read
  f32x4 o3fr[4][2];
#pragma unroll
  for (int mt = 0; mt < 4; ++mt) { o3fr[mt][0] = fz; o3fr[mt][1] = fz; }
  bf16x8 aaC[4];

#pragma unroll
  for (int rd = 0; rd <= 4; ++rd) {
    f32x4 cfE[4], cfO[4];
    if (rd < 4) {
#pragma unroll
      for (int mt = 0; mt < 4; ++mt) {
        cfE[mt] = __builtin_amdgcn_mfma_f32_16x16x32_bf16(az[mt], wlE, fz, 0, 0, 0);
        cfO[mt] = __builtin_amdgcn_mfma_f32_16x16x32_bf16(az[mt], wlO, fz, 0, 0, 0);
      }
    }
    if (rd > 0) {                           // C2(rd-1)
#pragma unroll
      for (int mt = 0; mt < 4; ++mt) {
        o3fr[mt][0] = __builtin_amdgcn_mfma_f32_16x16x32_bf16(aaC[mt], bw_u0,
                                                              o3fr[mt][0], 0, 0, 0);
        o3fr[mt][1] = __builtin_amdgcn_mfma_f32_16x16x32_bf16(aaC[mt], bw_u1,
                                                              o3fr[mt][1], 0, 0, 0);
      }
    }
    if (rd < 4) {
      unsigned short* Xb = X16 + (rd & 1) * 2560;
#pragma unroll
      for (int mt = 0; mt < 4; ++mt)
#pragma unroll
        for (int r = 0; r < 4; ++r) {
          float v0 = fmaxf(cfE[mt][r] + cE, 0.0f);
          float v1 = fmaxf(cfO[mt][r] + cO, 0.0f);
          *(unsigned*)(Xb + (mt * 16 + hi * 4 + r) * 40 + lo * 2) = pk2bf(v0, v1);
        }
      if (rd < 3) {
        wlEn = *(const bf16x8*)(L2p + ((2 * rd + 2) * 16 + lo) * 32 + hi * 8);
        wlOn = *(const bf16x8*)(L2p + ((2 * rd + 3) * 16 + lo) * 32 + hi * 8);
        cEn = b2[(2 * rd + 2) * 16 + lo];
        cOn = b2[(2 * rd + 3) * 16 + lo];
        bw_n0 = *(const bf16x8*)(W3p + ((2 * rd + 2) * 16 + lo) * 32 + hi * 8);
        bw_n1 = *(const bf16x8*)(W3p + ((2 * rd + 3) * 16 + lo) * 32 + hi * 8);
      }
      LFENCE();
#pragma unroll
      for (int mt = 0; mt < 4; ++mt)
        aaC[mt] = *(const bf16x8*)(Xb + (mt * 16 + lo) * 40 + hi * 8);
      bw_u0 = bw_c0; bw_u1 = bw_c1; bw_c0 = bw_n0; bw_c1 = bw_n1;
      wlE = wlEn; wlO = wlOn; cE = cEn; cO = cOn;
    }
  }

  // ---- Phase D (MFMA): o4 = relu(o3)@W4T, o3 staged as pairs into buf0
  float b3E = b3v[lo], b3O = b3v[16 + lo];
  unsigned short* Db = X16;                  // buf0 (in-order DS: safe)
#pragma unroll
  for (int mt = 0; mt < 4; ++mt)
#pragma unroll
    for (int r = 0; r < 4; ++r) {
      float v0 = fmaxf(o3fr[mt][0][r] + b3E, 0.0f);
      float v1 = fmaxf(o3fr[mt][1][r] + b3O, 0.0f);
      *(unsigned*)(Db + (mt * 16 + hi * 4 + r) * 40 + lo * 2) = pk2bf(v0, v1);
    }
  bf16x8 bw4 = *(const bf16x8*)(W4p + lo * 32 + hi * 8);
  float b4l = b4v[lo];
  LFENCE();
  bf16x8 aD[4];
#pragma unroll
  for (int mt = 0; mt < 4; ++mt)
    aD[mt] = *(const bf16x8*)(Db + (mt * 16 + lo) * 40 + hi * 8);
  f32x4 o4fr[4];
#pragma unroll
  for (int mt = 0; mt < 4; ++mt)
    o4fr[mt] = __builtin_amdgcn_mfma_f32_16x16x32_bf16(aD[mt], bw4, fz, 0, 0, 0);

  // ---- o4 (+b4, relu) -> O4f f32, per-lane pickup (reads issued before writes)
#pragma unroll
  for (int mt = 0; mt < 4; ++mt)
#pragma unroll
    for (int r = 0; r < 4; ++r)
      O4f[(mt * 16 + hi * 4 + r) * 17 + lo] = fmaxf(o4fr[mt][r] + b4l, 0.0f);
  LFENCE();
  float o4l[16];
#pragma unroll
  for (int q = 0; q < 16; ++q) o4l[q] = O4f[l * 17 + q];

  // ---- Phase E per-lane (uniform weights -> s_load)
#pragma unroll
  for (int e = 0; e < 3; ++e) {
    float acc = b5[e];
    const float* __restrict__ w5 = W5 + e * 16;
#pragma unroll
    for (int p = 0; p < 16; ++p) acc = fmaf(o4l[p], w5[p], acc);
    out[(pix0 + l) * 3 + e] = acc;
  }
}

extern "C" void kernel_launch(void* const* d_in, const int* in_sizes, int n_in,
                              void* d_out, int out_size, void* d_ws, size_t ws_size,
                              hipStream_t stream) {
  const float* coords = (const float*)d_in[0];
  const float* Bmat   = (const float*)d_in[1];
  const float* L1     = (const float*)d_in[2];
  const float* R1     = (const float*)d_in[3];
  const float* b1     = (const float*)d_in[4];
  const float* L2     = (const float*)d_in[5];
  const float* R2     = (const float*)d_in[6];
  const float* b2     = (const float*)d_in[7];
  const float* W3     = (const float*)d_in[8];
  const float* b3     = (const float*)d_in[9];
  const float* W4     = (const float*)d_in[10];
  const float* b4     = (const float*)d_in[11];
  const float* W5     = (const float*)d_in[12];
  const float* b5     = (const float*)d_in[13];

  prep_pack<<<227, 256, 0, stream>>>(R1, L1, R2, L2, W3, W4, d_ws);
  mlp_mfma<<<8192, 64, 0, stream>>>(coords, Bmat, b1, b2, b3, b4, W5, b5,
                                    d_ws, (float*)d_out);
}

// Round 7
// 156.004 us; speedup vs baseline: 1.9004x; 1.0080x over previous
//
#include <hip/hip_runtime.h>

// ImplicitMLP, all GEMMs (A,B1,B2,C1,C2,D) on MFMA bf16/fp32-acc; per-lane E.
// 64-thread 1-wave blocks, LDS 13312 B, r6 pipelined skeleton.
// Round 7: VALU-count reduction —
//  * biases b1/b2 folded into the K dimension (Y col65<-1.0, L1p[k=80]=b1;
//    Z col10<-1.0, L2p[k=10]=b2): one constant ds_write_b16 replaces 32 v_add
//    per rd and all bias scalar loads.
//  * v_fract_f32 builtin replaces floor+sub in the sin-argument reduction.
//  * phase-A kt loop fully unrolled, direct Bm indexing (no copy chains).
//
// LDS (13312 B), regions reused (single wave, in-order DS):
//   Y16 @0 [64][104] bf16 (13312) A->B1 transform, col-pair interleaved
//   X16 @0 [2][64][40] bf16 (2x5120) staging: B1->B2, C1->C2, o3->D (buf0)
//   O4f @0 [64][17] f32 (4352)    o4 hand-off to per-lane E
//
// ws (prep_pack), bf16 @short-idx:
//   R1p 0      [kt8][n80][k32]   k = interleaved sin/cos feature order
//   L1p 20480  [kt3][n256][k32]  k pair-permuted, r>=70 zero, r==80 -> b1[n]
//   R2p 45056  [rd8][n16][k32]   k pair-permuted, n>=10 zero
//   L2p 49152  [nt8][n16][k32]   straight k, k>=11 zero, k==10 -> b2[i]
//   W3p 53248  [rd4][s2][n16][k32] k pair-permuted
//   W4p 57344  [n16][k32]        k pair-permuted

typedef __attribute__((ext_vector_type(8))) short bf16x8;
typedef __attribute__((ext_vector_type(4))) float f32x4;
typedef __attribute__((ext_vector_type(4))) int i32x4;

#define LFENCE() asm volatile("s_waitcnt lgkmcnt(0)" ::: "memory")

__device__ inline unsigned short f2bf(float f) {       // RNE (prep)
  unsigned u = __float_as_uint(f);
  return (unsigned short)((u + 0x7FFFu + ((u >> 16) & 1u)) >> 16);
}

#if __has_builtin(__builtin_amdgcn_cvt_pk_bf16_f32)
typedef __attribute__((ext_vector_type(2))) __bf16 bf16x2;
__device__ inline unsigned pk2bf(float a, float b) {   // low=a, high=b (RNE)
  bf16x2 v = __builtin_amdgcn_cvt_pk_bf16_f32(a, b);
  return __builtin_bit_cast(unsigned, v);
}
#else
__device__ inline unsigned pk2bf(float a, float b) {   // round-half-up fallback
  return ((__float_as_uint(a) + 0x8000u) >> 16) |
         ((__float_as_uint(b) + 0x8000u) & 0xFFFF0000u);
}
#endif

__global__ __launch_bounds__(256) void prep_pack(
    const float* __restrict__ R1, const float* __restrict__ L1,
    const float* __restrict__ R2, const float* __restrict__ L2,
    const float* __restrict__ W3, const float* __restrict__ W4,
    const float* __restrict__ b1, const float* __restrict__ b2,
    void* __restrict__ ws) {
  unsigned short* w16 = (unsigned short*)ws;
  int e = blockIdx.x * 256 + threadIdx.x;
  if (e < 20480) {                       // R1p: B[k=feat][n=r]
    int kt = e / 2560, rem = e % 2560;
    int n = rem >> 5, oj = rem & 31;
    int k = kt * 32 + oj;
    int feat = (k & 1) ? 128 + (k >> 1) : (k >> 1);
    w16[e] = f2bf((n < 70) ? R1[n * 256 + feat] : 0.0f);
  } else if (e < 45056) {                // L1p: B[k=r][n=j], k pair-permuted
    int f = e - 20480;
    int kt = f / 8192, rem = f % 8192;
    int n = rem >> 5, oj = rem & 31;
    int r = kt * 32 + (oj & 1) * 16 + (oj >> 1);
    float v = (r < 70) ? L1[n * 70 + r] : (r == 80 ? b1[n] : 0.0f);
    w16[e] = f2bf(v);
  } else if (e < 49152) {                // R2p: B[k=j][n=t], k pair-permuted
    int g = e - 45056;
    int rd = g / 512, rem = g % 512;
    int n = rem >> 5, oj = rem & 31;
    int j = rd * 32 + (oj & 1) * 16 + (oj >> 1);
    w16[e] = f2bf((n < 10) ? R2[n * 256 + j] : 0.0f);
  } else if (e < 53248) {                // L2p: B[k=t][n=i], straight k
    int f = e - 49152;
    int k = f & 31, n = (f >> 5) & 15, nt = f >> 9;
    int i = nt * 16 + n;
    float v = (k < 10) ? L2[i * 10 + k] : (k == 10 ? b2[i] : 0.0f);
    w16[e] = f2bf(v);
  } else if (e < 57344) {                // W3p: B[k=i][n=q], k pair-permuted
    int f = e - 53248;
    int oj = f & 31, n = (f >> 5) & 15, s = (f >> 9) & 1, rd = f >> 10;
    int i = rd * 32 + (oj & 1) * 16 + (oj >> 1);
    w16[e] = f2bf(W3[(s * 16 + n) * 128 + i]);
  } else if (e < 57856) {                // W4p: B[k=q][n=p], k pair-permuted
    int f = e - 57344;
    int n = f >> 5, oj = f & 31;
    int q = (oj & 1) * 16 + (oj >> 1);
    w16[e] = f2bf(W4[n * 32 + q]);
  }
}

__global__ __launch_bounds__(64, 2) void mlp_mfma(
    const float* __restrict__ coords, const float* __restrict__ Bm,
    const float* __restrict__ b3v, const float* __restrict__ b4v,
    const float* __restrict__ W5, const float* __restrict__ b5,
    const void* __restrict__ ws, float* __restrict__ out) {
  const int l = threadIdx.x;
  const int lo = l & 15, hi = l >> 4;
  const int pix0 = blockIdx.x * 64;

  __shared__ __align__(16) char smem[13312];
  unsigned short* Y16 = (unsigned short*)smem;    // [64][104]
  unsigned short* X16 = (unsigned short*)smem;    // [2][64][40]
  float* O4f = (float*)smem;                      // [64][17]

  const unsigned short* R1p = (const unsigned short*)ws;
  const unsigned short* L1p = ((const unsigned short*)ws) + 20480;
  const unsigned short* R2p = ((const unsigned short*)ws) + 45056;
  const unsigned short* L2p = ((const unsigned short*)ws) + 49152;
  const unsigned short* W3p = ((const unsigned short*)ws) + 53248;
  const unsigned short* W4p = ((const unsigned short*)ws) + 57344;

  const f32x4 fz = {0.0f, 0.0f, 0.0f, 0.0f};

  float c0m[4], c1m[4];
#pragma unroll
  for (int mt = 0; mt < 4; ++mt) {
    int p = pix0 + mt * 16 + lo;
    int bb = p >> 12, hw = p & 4095;
    c0m[mt] = coords[bb * 8192 + hw];
    c1m[mt] = coords[bb * 8192 + 4096 + hw];
  }

  // ---- Phase A: y = X @ R1T, A-frags in registers (sin|cos packed)
  f32x4 y[4][5];
#pragma unroll
  for (int mt = 0; mt < 4; ++mt)
#pragma unroll
    for (int nt = 0; nt < 5; ++nt) y[mt][nt] = fz;

#pragma unroll
  for (int kt = 0; kt < 8; ++kt) {
    bf16x8 bfr[5];
#pragma unroll
    for (int nt = 0; nt < 5; ++nt)
      bfr[nt] = *(const bf16x8*)(R1p + (kt * 80 + nt * 16 + lo) * 32 + hi * 8);
    bf16x8 af[4];
#pragma unroll
    for (int mt = 0; mt < 4; ++mt) {
#pragma unroll
      for (int p = 0; p < 4; ++p) {
        int m = kt * 16 + hi * 4 + p;
        float u = fmaf(c0m[mt], Bm[m], c1m[mt] * Bm[128 + m]);
        float t = __builtin_amdgcn_fractf(u);  // v_sin/v_cos in revolutions
        float s = __builtin_amdgcn_sinf(t);
        float c = __builtin_amdgcn_cosf(t);
        ((unsigned*)&af[mt])[p] = pk2bf(s, c);
      }
    }
#pragma unroll
    for (int mt = 0; mt < 4; ++mt)
#pragma unroll
      for (int nt = 0; nt < 5; ++nt)
        y[mt][nt] = __builtin_amdgcn_mfma_f32_16x16x32_bf16(af[mt], bfr[nt],
                                                            y[mt][nt], 0, 0, 0);
  }

  // ---- y -> Y16 one-shot (pairs: (0,1),(2,3),(4,zero)), then bias-channel 1.0
#pragma unroll
  for (int mt = 0; mt < 4; ++mt)
#pragma unroll
    for (int r = 0; r < 4; ++r) {
      int row = mt * 16 + hi * 4 + r;
      *(unsigned*)(Y16 + row * 104 + lo * 2)      = pk2bf(y[mt][0][r], y[mt][1][r]);
      *(unsigned*)(Y16 + row * 104 + 32 + lo * 2) = pk2bf(y[mt][2][r], y[mt][3][r]);
      *(unsigned*)(Y16 + row * 104 + 64 + lo * 2) = pk2bf(y[mt][4][r], 0.0f);
    }
  Y16[l * 104 + 65] = 0x3F80;                // col65 <-> k=80: bias channel = 1.0

  // B-phase prologue weight loads (global/vmcnt: unaffected by LFENCE)
  bf16x8 WE[3], WO[3], WEn[3], WOn[3];
#pragma unroll
  for (int kt = 0; kt < 3; ++kt) {
    WE[kt] = *(const bf16x8*)(L1p + (kt * 256 + lo) * 32 + hi * 8);
    WO[kt] = *(const bf16x8*)(L1p + (kt * 256 + 16 + lo) * 32 + hi * 8);
  }
  bf16x8 br_c = *(const bf16x8*)(R2p + lo * 32 + hi * 8);
  bf16x8 br_u, br_n;

  LFENCE();                                  // drain Y writes
  bf16x8 ay[4][3];
#pragma unroll
  for (int mt = 0; mt < 4; ++mt)
#pragma unroll
    for (int kt = 0; kt < 3; ++kt)
      ay[mt][kt] = *(const bf16x8*)(Y16 + (mt * 16 + lo) * 104 + kt * 32 + hi * 8);
  // Y16 dead after these reads; X16 writes below are issued after (in-order DS).

  // ---- Phase B pipeline: B1(rd) MFMAs | B2(rd-1) MFMAs | write(rd) |
  //                        prefetch(rd+1) | fence | read(rd)
  f32x4 zfr[4];
#pragma unroll
  for (int mt = 0; mt < 4; ++mt) zfr[mt] = fz;
  bf16x8 aa[4];

#pragma unroll
  for (int rd = 0; rd <= 8; ++rd) {
    f32x4 cfE[4], cfO[4];
    if (rd < 8) {
#pragma unroll
      for (int mt = 0; mt < 4; ++mt) { cfE[mt] = fz; cfO[mt] = fz; }
#pragma unroll
      for (int kt = 0; kt < 3; ++kt)
#pragma unroll
        for (int mt = 0; mt < 4; ++mt) {
          cfE[mt] = __builtin_amdgcn_mfma_f32_16x16x32_bf16(ay[mt][kt], WE[kt],
                                                            cfE[mt], 0, 0, 0);
          cfO[mt] = __builtin_amdgcn_mfma_f32_16x16x32_bf16(ay[mt][kt], WO[kt],
                                                            cfO[mt], 0, 0, 0);
        }
    }
    if (rd > 0) {                           // B2(rd-1), reads covered above
#pragma unroll
      for (int mt = 0; mt < 4; ++mt)
        zfr[mt] = __builtin_amdgcn_mfma_f32_16x16x32_bf16(aa[mt], br_u,
                                                          zfr[mt], 0, 0, 0);
    }
    if (rd < 8) {
      unsigned short* Xb = X16 + (rd & 1) * 2560;
#pragma unroll
      for (int mt = 0; mt < 4; ++mt)
#pragma unroll
        for (int r = 0; r < 4; ++r) {
          float v0 = fmaxf(cfE[mt][r], 0.0f);   // bias already folded via k=80
          float v1 = fmaxf(cfO[mt][r], 0.0f);
          *(unsigned*)(Xb + (mt * 16 + hi * 4 + r) * 40 + lo * 2) = pk2bf(v0, v1);
        }
      if (rd < 7) {                         // prefetch rd+1 weights
#pragma unroll
        for (int kt = 0; kt < 3; ++kt) {
          WEn[kt] = *(const bf16x8*)(L1p + (kt * 256 + (2 * rd + 2) * 16 + lo) * 32 + hi * 8);
          WOn[kt] = *(const bf16x8*)(L1p + (kt * 256 + (2 * rd + 3) * 16 + lo) * 32 + hi * 8);
        }
        br_n = *(const bf16x8*)(R2p + ((rd + 1) * 16 + lo) * 32 + hi * 8);
      }
      LFENCE();                             // drain write(rd)
#pragma unroll
      for (int mt = 0; mt < 4; ++mt)
        aa[mt] = *(const bf16x8*)(Xb + (mt * 16 + lo) * 40 + hi * 8);
      br_u = br_c; br_c = br_n;
#pragma unroll
      for (int kt = 0; kt < 3; ++kt) { WE[kt] = WEn[kt]; WO[kt] = WOn[kt]; }
    }
  }

  // ---- z -> Z16 (buf0, straight cols; 16..31 zero; col10 = 1.0 bias channel)
  unsigned short* Z16 = X16;
#pragma unroll
  for (int mt = 0; mt < 4; ++mt)
#pragma unroll
    for (int r = 0; r < 4; ++r)
      Z16[(mt * 16 + hi * 4 + r) * 40 + lo] =
          (unsigned short)(pk2bf(zfr[mt][r], 0.0f) & 0xFFFFu);
  *(i32x4*)(Z16 + l * 40 + 16) = (i32x4){0, 0, 0, 0};
  *(i32x4*)(Z16 + l * 40 + 24) = (i32x4){0, 0, 0, 0};
  Z16[l * 40 + 10] = 0x3F80;                 // k=10: bias channel = 1.0

  // C-phase prologue loads
  bf16x8 wlE = *(const bf16x8*)(L2p + lo * 32 + hi * 8);
  bf16x8 wlO = *(const bf16x8*)(L2p + (16 + lo) * 32 + hi * 8);
  bf16x8 wlEn, wlOn;
  bf16x8 bw_c0 = *(const bf16x8*)(W3p + lo * 32 + hi * 8);
  bf16x8 bw_c1 = *(const bf16x8*)(W3p + (16 + lo) * 32 + hi * 8);
  bf16x8 bw_u0, bw_u1, bw_n0, bw_n1;

  LFENCE();                                  // drain Z writes
  bf16x8 az[4];
#pragma unroll
  for (int mt = 0; mt < 4; ++mt)
    az[mt] = *(const bf16x8*)(Z16 + (mt * 16 + lo) * 40 + hi * 8);

  // ---- Phase C pipeline: C1(rd) | C2(rd-1) | write(rd) | prefetch | fence | read
  f32x4 o3fr[4][2];
#pragma unroll
  for (int mt = 0; mt < 4; ++mt) { o3fr[mt][0] = fz; o3fr[mt][1] = fz; }
  bf16x8 aaC[4];

#pragma unroll
  for (int rd = 0; rd <= 4; ++rd) {
    f32x4 cfE[4], cfO[4];
    if (rd < 4) {
#pragma unroll
      for (int mt = 0; mt < 4; ++mt) {
        cfE[mt] = __builtin_amdgcn_mfma_f32_16x16x32_bf16(az[mt], wlE, fz, 0, 0, 0);
        cfO[mt] = __builtin_amdgcn_mfma_f32_16x16x32_bf16(az[mt], wlO, fz, 0, 0, 0);
      }
    }
    if (rd > 0) {                           // C2(rd-1)
#pragma unroll
      for (int mt = 0; mt < 4; ++mt) {
        o3fr[mt][0] = __builtin_amdgcn_mfma_f32_16x16x32_bf16(aaC[mt], bw_u0,
                                                              o3fr[mt][0], 0, 0, 0);
        o3fr[mt][1] = __builtin_amdgcn_mfma_f32_16x16x32_bf16(aaC[mt], bw_u1,
                                                              o3fr[mt][1], 0, 0, 0);
      }
    }
    if (rd < 4) {
      unsigned short* Xb = X16 + (rd & 1) * 2560;
#pragma unroll
      for (int mt = 0; mt < 4; ++mt)
#pragma unroll
        for (int r = 0; r < 4; ++r) {
          float v0 = fmaxf(cfE[mt][r], 0.0f);   // bias folded via k=10
          float v1 = fmaxf(cfO[mt][r], 0.0f);
          *(unsigned*)(Xb + (mt * 16 + hi * 4 + r) * 40 + lo * 2) = pk2bf(v0, v1);
        }
      if (rd < 3) {
        wlEn = *(const bf16x8*)(L2p + ((2 * rd + 2) * 16 + lo) * 32 + hi * 8);
        wlOn = *(const bf16x8*)(L2p + ((2 * rd + 3) * 16 + lo) * 32 + hi * 8);
        bw_n0 = *(const bf16x8*)(W3p + ((2 * rd + 2) * 16 + lo) * 32 + hi * 8);
        bw_n1 = *(const bf16x8*)(W3p + ((2 * rd + 3) * 16 + lo) * 32 + hi * 8);
      }
      LFENCE();
#pragma unroll
      for (int mt = 0; mt < 4; ++mt)
        aaC[mt] = *(const bf16x8*)(Xb + (mt * 16 + lo) * 40 + hi * 8);
      bw_u0 = bw_c0; bw_u1 = bw_c1; bw_c0 = bw_n0; bw_c1 = bw_n1;
      wlE = wlEn; wlO = wlOn;
    }
  }

  // ---- Phase D (MFMA): o4 = relu(o3+b3)@W4T, o3 staged as pairs into buf0
  float b3E = b3v[lo], b3O = b3v[16 + lo];
  unsigned short* Db = X16;                  // buf0 (in-order DS: safe)
#pragma unroll
  for (int mt = 0; mt < 4; ++mt)
#pragma unroll
    for (int r = 0; r < 4; ++r) {
      float v0 = fmaxf(o3fr[mt][0][r] + b3E, 0.0f);
      float v1 = fmaxf(o3fr[mt][1][r] + b3O, 0.0f);
      *(unsigned*)(Db + (mt * 16 + hi * 4 + r) * 40 + lo * 2) = pk2bf(v0, v1);
    }
  bf16x8 bw4 = *(const bf16x8*)(W4p + lo * 32 + hi * 8);
  float b4l = b4v[lo];
  LFENCE();
  bf16x8 aD[4];
#pragma unroll
  for (int mt = 0; mt < 4; ++mt)
    aD[mt] = *(const bf16x8*)(Db + (mt * 16 + lo) * 40 + hi * 8);
  f32x4 o4fr[4];
#pragma unroll
  for (int mt = 0; mt < 4; ++mt)
    o4fr[mt] = __builtin_amdgcn_mfma_f32_16x16x32_bf16(aD[mt], bw4, fz, 0, 0, 0);

  // ---- o4 (+b4, relu) -> O4f f32, per-lane pickup
#pragma unroll
  for (int mt = 0; mt < 4; ++mt)
#pragma unroll
    for (int r = 0; r < 4; ++r)
      O4f[(mt * 16 + hi * 4 + r) * 17 + lo] = fmaxf(o4fr[mt][r] + b4l, 0.0f);
  LFENCE();
  float o4l[16];
#pragma unroll
  for (int q = 0; q < 16; ++q) o4l[q] = O4f[l * 17 + q];

  // ---- Phase E per-lane (uniform weights -> s_load)
#pragma unroll
  for (int e = 0; e < 3; ++e) {
    float acc = b5[e];
    const float* __restrict__ w5 = W5 + e * 16;
#pragma unroll
    for (int p = 0; p < 16; ++p) acc = fmaf(o4l[p], w5[p], acc);
    out[(pix0 + l) * 3 + e] = acc;
  }
}

extern "C" void kernel_launch(void* const* d_in, const int* in_sizes, int n_in,
                              void* d_out, int out_size, void* d_ws, size_t ws_size,
                              hipStream_t stream) {
  const float* coords = (const float*)d_in[0];
  const float* Bmat   = (const float*)d_in[1];
  const float* L1     = (const float*)d_in[2];
  const float* R1     = (const float*)d_in[3];
  const float* b1     = (const float*)d_in[4];
  const float* L2     = (const float*)d_in[5];
  const float* R2     = (const float*)d_in[6];
  const float* b2     = (const float*)d_in[7];
  const float* W3     = (const float*)d_in[8];
  const float* b3     = (const float*)d_in[9];
  const float* W4     = (const float*)d_in[10];
  const float* b4     = (const float*)d_in[11];
  const float* W5     = (const float*)d_in[12];
  const float* b5     = (const float*)d_in[13];

  prep_pack<<<227, 256, 0, stream>>>(R1, L1, R2, L2, W3, W4, b1, b2, d_ws);
  mlp_mfma<<<8192, 64, 0, stream>>>(coords, Bmat, b3, b4, W5, b5,
                                    d_ws, (float*)d_out);
}